// Round 4
// baseline (1040.574 us; speedup 1.0000x reference)
//
#include <hip/hip_runtime.h>
#include <math.h>

// Problem constants (match reference)
#define BATCH 2
#define SEQ   2048
#define EMB   1024
#define HEADS 16
#define DH    64
// tokens N = BATCH*SEQ = 4096

// ---------------------------------------------------------------------------
// Kernel 1: QKV projection.
//   q[b,h,t,d] = sum_c x[b,t,c] * Wq[h,c,d]   (same for k, v)
// Output layout: qkv[m][b][h][t][d], m in {0=q,1=k,2=v}, each plane T*DH.
// grid = (SEQ/128, BATCH*3*HEADS), block = 256.
// Tile: 128 tokens x 64 dims, K-chunks of 32, 8x4 register blocking.
// ---------------------------------------------------------------------------
__global__ __launch_bounds__(256) void qkv_proj(
    const float* __restrict__ x,
    const float* __restrict__ Wq,
    const float* __restrict__ Wk,
    const float* __restrict__ Wv,
    float* __restrict__ qkv)
{
    __shared__ float XT[32][132];  // [k-chunk][token], transposed, padded
    __shared__ float Ws[32][68];   // [k-chunk][d], padded

    const int t0  = blockIdx.x * 128;
    const int gy  = blockIdx.y;            // b*48 + m*16 + h
    const int b   = gy / 48;
    const int rem = gy % 48;
    const int m   = rem / 16;
    const int h   = rem % 16;

    const float* W = (m == 0 ? Wq : (m == 1 ? Wk : Wv)) + (size_t)h * (EMB * DH);
    float* out = qkv + ((size_t)m * BATCH * HEADS + (size_t)b * HEADS + h) * (SEQ * DH)
                     + (size_t)t0 * DH;
    const float* xb = x + ((size_t)b * SEQ + t0) * EMB;

    const int tid  = threadIdx.x;
    const int trow = tid >> 4;   // 0..15 : token group (8 tokens each)
    const int tcol = tid & 15;   // 0..15 : dim group (4 dims each)

    float acc[8][4];
#pragma unroll
    for (int i = 0; i < 8; ++i)
#pragma unroll
        for (int j = 0; j < 4; ++j) acc[i][j] = 0.f;

    for (int c0 = 0; c0 < EMB; c0 += 32) {
        __syncthreads();
        // stage X tile 128x32 -> XT[kk][tok]
#pragma unroll
        for (int k = 0; k < 4; ++k) {
            int v  = tid + k * 256;         // float4 index, 0..1023
            int i  = v >> 3;                // token row 0..127
            int c4 = (v & 7) * 4;           // k offset 0..28
            const float4 xv = *reinterpret_cast<const float4*>(&xb[(size_t)i * EMB + c0 + c4]);
            XT[c4 + 0][i] = xv.x; XT[c4 + 1][i] = xv.y;
            XT[c4 + 2][i] = xv.z; XT[c4 + 3][i] = xv.w;
        }
        // stage W tile 32x64 -> Ws[kk][d]
#pragma unroll
        for (int k = 0; k < 2; ++k) {
            int v  = tid + k * 256;         // 0..511
            int j  = v >> 4;                // k row 0..31
            int d4 = (v & 15) * 4;          // d offset 0..60
            *reinterpret_cast<float4*>(&Ws[j][d4]) =
                *reinterpret_cast<const float4*>(&W[(size_t)(c0 + j) * DH + d4]);
        }
        __syncthreads();
#pragma unroll
        for (int kk = 0; kk < 32; ++kk) {
            float4 a0 = *reinterpret_cast<const float4*>(&XT[kk][trow * 8]);
            float4 a1 = *reinterpret_cast<const float4*>(&XT[kk][trow * 8 + 4]);
            float4 bb = *reinterpret_cast<const float4*>(&Ws[kk][tcol * 4]);
            float a[8] = {a0.x, a0.y, a0.z, a0.w, a1.x, a1.y, a1.z, a1.w};
            float bj[4] = {bb.x, bb.y, bb.z, bb.w};
#pragma unroll
            for (int i = 0; i < 8; ++i)
#pragma unroll
                for (int j = 0; j < 4; ++j)
                    acc[i][j] = fmaf(a[i], bj[j], acc[i][j]);
        }
    }

#pragma unroll
    for (int i = 0; i < 8; ++i) {
        float4 o = {acc[i][0], acc[i][1], acc[i][2], acc[i][3]};
        *reinterpret_cast<float4*>(&out[(size_t)(trow * 8 + i) * DH + tcol * 4]) = o;
    }
}

// ---------------------------------------------------------------------------
// Kernel 2: causal flash attention (fp32), scale = EMB^-0.5 = 1/32.
// One block per (b, h, q-tile of 64). Online softmax, k-tiles of 64, causal
// skip (only kt <= qt). KT and PT share one LDS buffer (union) to stay under
// the 64KB static-LDS limit. Writes Y[b][t][h*64+d] (concat-head layout).
// grid = (SEQ/64, BATCH*HEADS), block = 256.
// ---------------------------------------------------------------------------
__global__ __launch_bounds__(256) void attn_fwd(
    const float* __restrict__ qkv,
    float* __restrict__ Y)
{
    __shared__ float QT[64][68];    // Q transposed [d][tq], pre-scaled
    __shared__ float KPT[64][68];   // phase 1: K^T [d][tk]; phase 2: P^T [tk][tq]
    __shared__ float Vs[64][68];    // V natural [tk][d]

    const int qt = (gridDim.x - 1) - blockIdx.x;   // heavy tiles first
    const int bh = blockIdx.y;                     // b*HEADS + h
    const int b  = bh >> 4;
    const int h  = bh & 15;

    const size_t plane = (size_t)SEQ * DH;
    const float* Q = qkv + (size_t)bh * plane;
    const float* K = qkv + (size_t)(BATCH * HEADS) * plane + (size_t)bh * plane;
    const float* V = qkv + 2 * (size_t)(BATCH * HEADS) * plane + (size_t)bh * plane;

    const int tid = threadIdx.x;
    const int rg  = tid >> 4;   // 0..15: row group (4 q-rows)
    const int cg  = tid & 15;   // 0..15: col group (4 cols)
    const float scale = 0.03125f;  // EMB^-0.5

    // stage Q tile (scaled), transposed
#pragma unroll
    for (int k = 0; k < 4; ++k) {
        int v  = tid + k * 256;
        int t  = v >> 4;
        int d4 = (v & 15) * 4;
        const float4 qv = *reinterpret_cast<const float4*>(&Q[((size_t)qt * 64 + t) * DH + d4]);
        QT[d4 + 0][t] = qv.x * scale; QT[d4 + 1][t] = qv.y * scale;
        QT[d4 + 2][t] = qv.z * scale; QT[d4 + 3][t] = qv.w * scale;
    }

    float o[4][4];
    float m_run[4], l_run[4];
#pragma unroll
    for (int i = 0; i < 4; ++i) {
        m_run[i] = -3e38f;
        l_run[i] = 0.f;
#pragma unroll
        for (int j = 0; j < 4; ++j) o[i][j] = 0.f;
    }

    for (int kt = 0; kt <= qt; ++kt) {
        __syncthreads();   // prev iter's PV reads (KPT,Vs) done; Q stage done (kt=0)
        // stage K transposed + V natural
#pragma unroll
        for (int k = 0; k < 4; ++k) {
            int v  = tid + k * 256;
            int t  = v >> 4;
            int d4 = (v & 15) * 4;
            const float4 kv = *reinterpret_cast<const float4*>(&K[((size_t)kt * 64 + t) * DH + d4]);
            KPT[d4 + 0][t] = kv.x; KPT[d4 + 1][t] = kv.y;
            KPT[d4 + 2][t] = kv.z; KPT[d4 + 3][t] = kv.w;
            *reinterpret_cast<float4*>(&Vs[t][d4]) =
                *reinterpret_cast<const float4*>(&V[((size_t)kt * 64 + t) * DH + d4]);
        }
        __syncthreads();

        // S = (Q*scale) K^T  (64x64 tile, 4x4 per thread)
        float s[4][4];
#pragma unroll
        for (int i = 0; i < 4; ++i)
#pragma unroll
            for (int j = 0; j < 4; ++j) s[i][j] = 0.f;

        for (int kk = 0; kk < 64; ++kk) {
            float4 qv = *reinterpret_cast<const float4*>(&QT[kk][rg * 4]);
            float4 kv = *reinterpret_cast<const float4*>(&KPT[kk][cg * 4]);
            float qa[4] = {qv.x, qv.y, qv.z, qv.w};
            float kb[4] = {kv.x, kv.y, kv.z, kv.w};
#pragma unroll
            for (int i = 0; i < 4; ++i)
#pragma unroll
                for (int j = 0; j < 4; ++j)
                    s[i][j] = fmaf(qa[i], kb[j], s[i][j]);
        }

        if (kt == qt) {   // causal mask inside diagonal tile
#pragma unroll
            for (int i = 0; i < 4; ++i)
#pragma unroll
                for (int j = 0; j < 4; ++j)
                    if (cg * 4 + j > rg * 4 + i) s[i][j] = -3e38f;
        }

        __syncthreads();   // all waves finished reading KPT as K^T

        // online softmax; write P^T into KPT
#pragma unroll
        for (int i = 0; i < 4; ++i) {
            float tmax = fmaxf(fmaxf(s[i][0], s[i][1]), fmaxf(s[i][2], s[i][3]));
#pragma unroll
            for (int off = 1; off < 16; off <<= 1)
                tmax = fmaxf(tmax, __shfl_xor(tmax, off, 16));
            float mo = m_run[i];
            float mn = fmaxf(mo, tmax);
            float sc = __expf(mo - mn);       // 0 when mo == -3e38
            int r = rg * 4 + i;
            float psum = 0.f;
#pragma unroll
            for (int j = 0; j < 4; ++j) {
                float p = __expf(s[i][j] - mn);
                KPT[cg * 4 + j][r] = p;       // P^T[tk][tq]
                psum += p;
            }
#pragma unroll
            for (int off = 1; off < 16; off <<= 1)
                psum += __shfl_xor(psum, off, 16);
#pragma unroll
            for (int j = 0; j < 4; ++j) o[i][j] *= sc;
            m_run[i] = mn;
            l_run[i] = l_run[i] * sc + psum;
        }
        // note: no barrier needed before PV — each wave reads back only the
        // P^T columns it wrote itself (rows 16*wave..16*wave+15), Vs synced above.

        // O += P V
        for (int kk = 0; kk < 64; ++kk) {
            float4 pv = *reinterpret_cast<const float4*>(&KPT[kk][rg * 4]);
            float4 vv = *reinterpret_cast<const float4*>(&Vs[kk][cg * 4]);
            float pa[4] = {pv.x, pv.y, pv.z, pv.w};
            float vb[4] = {vv.x, vv.y, vv.z, vv.w};
#pragma unroll
            for (int i = 0; i < 4; ++i)
#pragma unroll
                for (int j = 0; j < 4; ++j)
                    o[i][j] = fmaf(pa[i], vb[j], o[i][j]);
        }
    }

    // normalize + store to concat-head layout Y[b][t][h*DH + d]
#pragma unroll
    for (int i = 0; i < 4; ++i) {
        int r = rg * 4 + i;
        float inv = 1.f / l_run[i];
        float4 ov = {o[i][0] * inv, o[i][1] * inv, o[i][2] * inv, o[i][3] * inv};
        size_t t = (size_t)b * SEQ + (size_t)qt * 64 + r;
        *reinterpret_cast<float4*>(&Y[t * EMB + h * DH + cg * 4]) = ov;
    }
}

// ---------------------------------------------------------------------------
// Kernel 3: output projection. out[n,e] = sum_c Y[n,c] * Wo[e,c] + bo[e]
// grid = (N/128, EMB/64), block = 256. Same tiling as kernel 1; Wo is
// transposed into LDS (B-operand is Wo^T).
// ---------------------------------------------------------------------------
__global__ __launch_bounds__(256) void out_proj(
    const float* __restrict__ Y,
    const float* __restrict__ Wo,
    const float* __restrict__ bo,
    float* __restrict__ out)
{
    __shared__ float XT[32][132];
    __shared__ float Ws[32][68];   // [c][e]

    const int n0 = blockIdx.x * 128;
    const int e0 = blockIdx.y * 64;
    const int tid  = threadIdx.x;
    const int trow = tid >> 4;
    const int tcol = tid & 15;

    float acc[8][4];
#pragma unroll
    for (int i = 0; i < 8; ++i)
#pragma unroll
        for (int j = 0; j < 4; ++j) acc[i][j] = 0.f;

    for (int c0 = 0; c0 < EMB; c0 += 32) {
        __syncthreads();
#pragma unroll
        for (int k = 0; k < 4; ++k) {
            int v  = tid + k * 256;
            int i  = v >> 3;
            int c4 = (v & 7) * 4;
            const float4 xv = *reinterpret_cast<const float4*>(&Y[(size_t)(n0 + i) * EMB + c0 + c4]);
            XT[c4 + 0][i] = xv.x; XT[c4 + 1][i] = xv.y;
            XT[c4 + 2][i] = xv.z; XT[c4 + 3][i] = xv.w;
        }
#pragma unroll
        for (int k = 0; k < 2; ++k) {
            int v  = tid + k * 256;     // 0..511
            int er = v >> 3;            // e row 0..63
            int c4 = (v & 7) * 4;       // c offset 0..28
            const float4 wv = *reinterpret_cast<const float4*>(&Wo[(size_t)(e0 + er) * EMB + c0 + c4]);
            Ws[c4 + 0][er] = wv.x; Ws[c4 + 1][er] = wv.y;
            Ws[c4 + 2][er] = wv.z; Ws[c4 + 3][er] = wv.w;
        }
        __syncthreads();
#pragma unroll
        for (int kk = 0; kk < 32; ++kk) {
            float4 a0 = *reinterpret_cast<const float4*>(&XT[kk][trow * 8]);
            float4 a1 = *reinterpret_cast<const float4*>(&XT[kk][trow * 8 + 4]);
            float4 bb = *reinterpret_cast<const float4*>(&Ws[kk][tcol * 4]);
            float a[8] = {a0.x, a0.y, a0.z, a0.w, a1.x, a1.y, a1.z, a1.w};
            float bj[4] = {bb.x, bb.y, bb.z, bb.w};
#pragma unroll
            for (int i = 0; i < 8; ++i)
#pragma unroll
                for (int j = 0; j < 4; ++j)
                    acc[i][j] = fmaf(a[i], bj[j], acc[i][j]);
        }
    }

    const float4 bias = *reinterpret_cast<const float4*>(&bo[e0 + tcol * 4]);
#pragma unroll
    for (int i = 0; i < 8; ++i) {
        float4 ov = {acc[i][0] + bias.x, acc[i][1] + bias.y,
                     acc[i][2] + bias.z, acc[i][3] + bias.w};
        *reinterpret_cast<float4*>(&out[(size_t)(n0 + trow * 8 + i) * EMB + e0 + tcol * 4]) = ov;
    }
}

// ---------------------------------------------------------------------------
extern "C" void kernel_launch(void* const* d_in, const int* in_sizes, int n_in,
                              void* d_out, int out_size, void* d_ws, size_t ws_size,
                              hipStream_t stream)
{
    const float* x  = (const float*)d_in[0];
    const float* Wq = (const float*)d_in[1];
    const float* Wk = (const float*)d_in[2];
    const float* Wv = (const float*)d_in[3];
    const float* Wo = (const float*)d_in[4];
    const float* bo = (const float*)d_in[5];
    float* out = (float*)d_out;

    float* ws  = (float*)d_ws;
    const size_t plane = (size_t)BATCH * HEADS * SEQ * DH;  // 4,194,304 floats
    float* qkv = ws;              // 3 * plane floats (Q,K,V)
    float* Y   = ws + 3 * plane;  // plane floats (attention output, concat layout)

    qkv_proj<<<dim3(SEQ / 128, BATCH * 3 * HEADS), 256, 0, stream>>>(x, Wq, Wk, Wv, qkv);
    attn_fwd<<<dim3(SEQ / 64, BATCH * HEADS), 256, 0, stream>>>(qkv, Y);
    out_proj<<<dim3((BATCH * SEQ) / 128, EMB / 64), 256, 0, stream>>>(Y, Wo, bo, out);
}

// Round 6
// 227.195 us; speedup vs baseline: 4.5801x; 4.5801x over previous
//
#include <hip/hip_runtime.h>
#include <math.h>
#include <stdint.h>

#define BATCH 2
#define SEQ   2048
#define EMB   1024
#define HEADS 16
#define DH    64
#define NTOK  (BATCH*SEQ)   // 4096
#define NCOL  (3*EMB)       // 3072: qkv_tok columns (q|k|v, each h-major, d-minor)

typedef float  f32x4  __attribute__((ext_vector_type(4)));
typedef short  bf16x8 __attribute__((ext_vector_type(8)));

#define MFMA(a,b,c) __builtin_amdgcn_mfma_f32_16x16x32_bf16((a),(b),(c),0,0,0)

__device__ __forceinline__ ushort f2bf(float f) {
    union { float f; uint32_t u; } v; v.f = f;
    uint32_t u = v.u;
    return (ushort)((u + 0x7FFFu + ((u >> 16) & 1u)) >> 16);   // RNE
}

// async global->LDS, 16B per lane; LDS dest = wave-uniform base + lane*16
__device__ __forceinline__ void gload16(const void* g, void* l) {
    __builtin_amdgcn_global_load_lds(
        (const __attribute__((address_space(1))) void*)g,
        (__attribute__((address_space(3))) void*)l, 16, 0, 0);
}

// ---------------------------------------------------------------------------
// fp32 -> bf16 copy-convert, 8 elems/thread. n8 = n/8 (exact).
// ---------------------------------------------------------------------------
__global__ __launch_bounds__(256) void f32_to_bf16(
    const float* __restrict__ src, ushort* __restrict__ dst, int n8)
{
    int i = blockIdx.x * 256 + threadIdx.x;
    if (i >= n8) return;
    const float4* s = (const float4*)src + (size_t)i * 2;
    float4 a = s[0], b = s[1];
    alignas(16) ushort o[8] = {f2bf(a.x), f2bf(a.y), f2bf(a.z), f2bf(a.w),
                               f2bf(b.x), f2bf(b.y), f2bf(b.z), f2bf(b.w)};
    *(uint4*)(dst + (size_t)i * 8) = *(const uint4*)o;
}

// ---------------------------------------------------------------------------
// Build W_allT [3072][1024] bf16: row n=(m*16+h)*64+d, col c.  (k-contiguous
// B^T operand for the QKV GEMM.)  grid (16 c-tiles, 48 (m,h)), block 256.
// ---------------------------------------------------------------------------
__global__ __launch_bounds__(256) void build_wallt(
    const float* __restrict__ Wq, const float* __restrict__ Wk,
    const float* __restrict__ Wv, ushort* __restrict__ WT)
{
    __shared__ float Tf[64][72];
    const int c0 = blockIdx.x * 64;
    const int gy = blockIdx.y;                  // m*16 + h
    const int m  = gy >> 4;
    const float* W = (m == 0 ? Wq : (m == 1 ? Wk : Wv)) + (size_t)(gy & 15) * (EMB * DH);

    const int tid = threadIdx.x, r = tid >> 2, seg = tid & 3;
    const float* src = W + (size_t)(c0 + r) * DH + seg * 16;
#pragma unroll
    for (int j = 0; j < 4; ++j) {
        float4 v = *(const float4*)(src + j * 4);
        int d = seg * 16 + j * 4;
        Tf[d+0][r] = v.x; Tf[d+1][r] = v.y; Tf[d+2][r] = v.z; Tf[d+3][r] = v.w;
    }
    __syncthreads();
    const int d = tid >> 2;
    alignas(16) ushort o[16];
#pragma unroll
    for (int j = 0; j < 16; ++j) o[j] = f2bf(Tf[d][seg * 16 + j]);
    ushort* dst = WT + (size_t)(gy * 64 + d) * EMB + c0 + seg * 16;
    *(uint4*)dst       = *(const uint4*)o;
    *(uint4*)(dst + 8) = *(const uint4*)(o + 8);
}

// ---------------------------------------------------------------------------
// QKV GEMM: C[4096][3072] = xbf[4096][1024] * W_allT^T, bf16 MFMA 16x16x32.
// 128x128 tile, BK=64, 4 waves 2x2, 4x4 frags/wave. Q columns (n<1024)
// pre-scaled by EMB^-0.5. Epilogue staged through LDS for coalesced stores.
// ---------------------------------------------------------------------------
__global__ __launch_bounds__(256) void qkv_gemm(
    const ushort* __restrict__ A, const ushort* __restrict__ BT,
    ushort* __restrict__ C)
{
    __shared__ char smem[34816];
    ushort* Ab = (ushort*)smem;               // [128][64]
    ushort* Bb = (ushort*)(smem + 16384);     // [128][64]
    ushort* Cs = (ushort*)smem;               // [128][136] (epilogue reuse)

    const int n0 = blockIdx.x * 128, m0 = blockIdx.y * 128;
    const int tid = threadIdx.x, lane = tid & 63, wid = tid >> 6;
    const int wr = wid >> 1, wc = wid & 1;
    const int lr = lane >> 3, lk = (lane & 7) * 8;

    f32x4 acc[4][4];
#pragma unroll
    for (int i = 0; i < 4; ++i)
#pragma unroll
        for (int j = 0; j < 4; ++j) acc[i][j] = (f32x4){0.f, 0.f, 0.f, 0.f};

    for (int k0 = 0; k0 < EMB; k0 += 64) {
#pragma unroll
        for (int t = 0; t < 4; ++t) {
            int c = wid * 4 + t;
            int row = c * 8 + lr;
            gload16(A  + (size_t)(m0 + row) * EMB + k0 + lk, Ab + c * 512);
            gload16(BT + (size_t)(n0 + row) * EMB + k0 + lk, Bb + c * 512);
        }
        __syncthreads();
#pragma unroll
        for (int ks = 0; ks < 2; ++ks) {
            bf16x8 fa[4], fb[4];
#pragma unroll
            for (int f = 0; f < 4; ++f) {
                int koff = ks * 32 + (lane >> 4) * 8;
                fa[f] = *(const bf16x8*)(Ab + (wr * 64 + f * 16 + (lane & 15)) * 64 + koff);
                fb[f] = *(const bf16x8*)(Bb + (wc * 64 + f * 16 + (lane & 15)) * 64 + koff);
            }
#pragma unroll
            for (int i = 0; i < 4; ++i)
#pragma unroll
                for (int j = 0; j < 4; ++j)
                    acc[i][j] = MFMA(fa[i], fb[j], acc[i][j]);
        }
        __syncthreads();
    }

    const float sc = (n0 < EMB) ? 0.03125f : 1.0f;   // scale Q by EMB^-0.5
#pragma unroll
    for (int i = 0; i < 4; ++i) {
        int row = wr * 64 + i * 16 + (lane >> 4) * 4;
#pragma unroll
        for (int j = 0; j < 4; ++j) {
            int col = wc * 64 + j * 16 + (lane & 15);
#pragma unroll
            for (int r = 0; r < 4; ++r)
                Cs[(row + r) * 136 + col] = f2bf(acc[i][j][r] * sc);
        }
    }
    __syncthreads();
#pragma unroll
    for (int it = 0; it < 8; ++it) {
        int c = tid + it * 256;                 // 0..2047 16B-chunks
        int row = c >> 4, off = (c & 15) * 8;
        *(uint4*)(C + (size_t)(m0 + row) * NCOL + n0 + off) =
            *(const uint4*)(Cs + row * 136 + off);
    }
}

// ---------------------------------------------------------------------------
// V transpose: VT[bh][d][t] <- qkv_tok[b*2048+t][2048+h*64+d].
// grid (32 t-tiles, 32 bh), block 256.
// ---------------------------------------------------------------------------
__global__ __launch_bounds__(256) void transpose_v(
    const ushort* __restrict__ C, ushort* __restrict__ VT)
{
    __shared__ ushort Tu[64][72];
    const int t0 = blockIdx.x * 64;
    const int bh = blockIdx.y;
    const int b = bh >> 4, h = bh & 15;
    const int tid = threadIdx.x, r = tid >> 2, seg = tid & 3;

    const ushort* src = C + (size_t)(b * SEQ + t0 + r) * NCOL + 2 * EMB + h * DH + seg * 16;
    alignas(16) ushort tmp[16];
    *(uint4*)tmp       = *(const uint4*)src;
    *(uint4*)(tmp + 8) = *(const uint4*)(src + 8);
#pragma unroll
    for (int j = 0; j < 16; ++j) Tu[seg * 16 + j][r] = tmp[j];   // Tu[d][t]
    __syncthreads();
    const int d = tid >> 2;
    alignas(16) ushort o[16];
#pragma unroll
    for (int j = 0; j < 16; ++j) o[j] = Tu[d][seg * 16 + j];
    ushort* dst = VT + (size_t)bh * (DH * SEQ) + (size_t)d * SEQ + t0 + seg * 16;
    *(uint4*)dst       = *(const uint4*)o;
    *(uint4*)(dst + 8) = *(const uint4*)(o + 8);
}

// ---------------------------------------------------------------------------
// MFMA flash attention. Block = 4 waves; QBLK=128 (32 q-rows/wave), KVBLK=64.
// S = Q K^T and O += P V via 16x16x32 bf16 MFMA; online softmax with 16-lane
// shfl groups (C-layout: col=lane&15, row=(lane>>4)*4+reg). Causal skip.
// ---------------------------------------------------------------------------
__global__ __launch_bounds__(256) void attn_mfma(
    const ushort* __restrict__ C, const ushort* __restrict__ VT,
    ushort* __restrict__ Y)
{
    __shared__ ushort KT[64 * 64];        // [kv][d]
    __shared__ ushort VTl[64 * 64];       // [d][kv]
    __shared__ ushort Pl[4][32 * 64];     // per-wave P [q][kv]

    const int qt = 15 - blockIdx.x;       // heavy tiles first
    const int bh = blockIdx.y;
    const int b = bh >> 4, h = bh & 15;
    const int tid = threadIdx.x, lane = tid & 63, wid = tid >> 6;
    const int q0 = qt * 128;
    const int qr0 = q0 + wid * 32;
    const int lr = lane >> 3, lk8 = (lane & 7) * 8;

    // Q fragments, reused for all k-tiles (pre-scaled in GEMM)
    bf16x8 qa[2][2];
#pragma unroll
    for (int fr = 0; fr < 2; ++fr)
#pragma unroll
        for (int fk = 0; fk < 2; ++fk) {
            int row = b * SEQ + qr0 + fr * 16 + (lane & 15);
            int col = h * DH + fk * 32 + (lane >> 4) * 8;
            qa[fr][fk] = *(const bf16x8*)(C + (size_t)row * NCOL + col);
        }

    f32x4 of[2][4];
    float mst[2][4], lst[2][4];
#pragma unroll
    for (int i = 0; i < 2; ++i)
#pragma unroll
        for (int r = 0; r < 4; ++r) { mst[i][r] = -3.0e38f; lst[i][r] = 0.f; }
#pragma unroll
    for (int i = 0; i < 2; ++i)
#pragma unroll
        for (int j = 0; j < 4; ++j) of[i][j] = (f32x4){0.f, 0.f, 0.f, 0.f};

    const int nkt = 2 * (qt + 1);
    for (int kt = 0; kt < nkt; ++kt) {
        const int kv0 = kt * 64;
        // stage K[kv][d] and VT[d][kv] tiles (8KB each, 8 chunks, 2/wave)
#pragma unroll
        for (int t = 0; t < 2; ++t) {
            int c = wid * 2 + t;
            int row = c * 8 + lr;
            gload16(C  + (size_t)(b * SEQ + kv0 + row) * NCOL + EMB + h * DH + lk8,
                    KT + c * 512);
            gload16(VT + (size_t)bh * (DH * SEQ) + (size_t)row * SEQ + kv0 + lk8,
                    VTl + c * 512);
        }
        __syncthreads();

        if (kv0 <= qr0 + 31) {            // wave has unmasked work in this tile
            // S = Q K^T
            f32x4 sa[2][4];
#pragma unroll
            for (int i = 0; i < 2; ++i)
#pragma unroll
                for (int j = 0; j < 4; ++j) sa[i][j] = (f32x4){0.f, 0.f, 0.f, 0.f};
#pragma unroll
            for (int ks = 0; ks < 2; ++ks) {
                bf16x8 kb[4];
#pragma unroll
                for (int fc = 0; fc < 4; ++fc)
                    kb[fc] = *(const bf16x8*)(KT + (fc * 16 + (lane & 15)) * 64
                                                 + ks * 32 + (lane >> 4) * 8);
#pragma unroll
                for (int fr = 0; fr < 2; ++fr)
#pragma unroll
                    for (int fc = 0; fc < 4; ++fc)
                        sa[fr][fc] = MFMA(qa[fr][ks], kb[fc], sa[fr][fc]);
            }
            // causal mask (diagonal-spanning tiles only)
            if (kv0 + 63 > qr0) {
#pragma unroll
                for (int fr = 0; fr < 2; ++fr)
#pragma unroll
                    for (int fc = 0; fc < 4; ++fc) {
                        int colg = kv0 + fc * 16 + (lane & 15);
#pragma unroll
                        for (int r = 0; r < 4; ++r) {
                            int rowg = qr0 + fr * 16 + (lane >> 4) * 4 + r;
                            if (colg > rowg) sa[fr][fc][r] = -3.0e38f;
                        }
                    }
            }
            // online softmax; P -> bf16 -> wave-local LDS
#pragma unroll
            for (int fr = 0; fr < 2; ++fr) {
#pragma unroll
                for (int r = 0; r < 4; ++r) {
                    float mx = fmaxf(fmaxf(sa[fr][0][r], sa[fr][1][r]),
                                     fmaxf(sa[fr][2][r], sa[fr][3][r]));
#pragma unroll
                    for (int m = 1; m < 16; m <<= 1)
                        mx = fmaxf(mx, __shfl_xor(mx, m));
                    float mo = mst[fr][r];
                    float mn = fmaxf(mo, mx);
                    float scl = __expf(mo - mn);          // 0 on first tile
                    float ps = 0.f;
                    ushort pb[4];
#pragma unroll
                    for (int fc = 0; fc < 4; ++fc) {
                        float p = __expf(sa[fr][fc][r] - mn);
                        ps += p;
                        pb[fc] = f2bf(p);
                    }
#pragma unroll
                    for (int m = 1; m < 16; m <<= 1)
                        ps += __shfl_xor(ps, m);
                    mst[fr][r] = mn;
                    lst[fr][r] = lst[fr][r] * scl + ps;
#pragma unroll
                    for (int fd = 0; fd < 4; ++fd) of[fr][fd][r] *= scl;
                    int prow = fr * 16 + (lane >> 4) * 4 + r;
#pragma unroll
                    for (int fc = 0; fc < 4; ++fc)
                        Pl[wid][prow * 64 + fc * 16 + (lane & 15)] = pb[fc];
                }
            }
            // O += P V  (P read back wave-locally)
#pragma unroll
            for (int ks = 0; ks < 2; ++ks) {
                bf16x8 pa[2], vb[4];
#pragma unroll
                for (int fr = 0; fr < 2; ++fr)
                    pa[fr] = *(const bf16x8*)(&Pl[wid][(fr * 16 + (lane & 15)) * 64
                                                       + ks * 32 + (lane >> 4) * 8]);
#pragma unroll
                for (int fd = 0; fd < 4; ++fd)
                    vb[fd] = *(const bf16x8*)(VTl + (fd * 16 + (lane & 15)) * 64
                                                  + ks * 32 + (lane >> 4) * 8);
#pragma unroll
                for (int fr = 0; fr < 2; ++fr)
#pragma unroll
                    for (int fd = 0; fd < 4; ++fd)
                        of[fr][fd] = MFMA(pa[fr], vb[fd], of[fr][fd]);
            }
        }
        __syncthreads();                  // protect KT/VTl before restage
    }

    // normalize + store Y (concat-head, bf16)
#pragma unroll
    for (int fr = 0; fr < 2; ++fr) {
        float inv[4];
#pragma unroll
        for (int r = 0; r < 4; ++r) inv[r] = 1.f / lst[fr][r];
#pragma unroll
        for (int fd = 0; fd < 4; ++fd) {
            int col = h * DH + fd * 16 + (lane & 15);
#pragma unroll
            for (int r = 0; r < 4; ++r) {
                int row = b * SEQ + qr0 + fr * 16 + (lane >> 4) * 4 + r;
                Y[(size_t)row * EMB + col] = f2bf(of[fr][fd][r] * inv[r]);
            }
        }
    }
}

// ---------------------------------------------------------------------------
// Output projection: out[4096][1024] = Ybf * Wo^T + bo (fp32 out).
// Same GEMM core; Wo natural layout is already the k-contiguous B^T.
// ---------------------------------------------------------------------------
__global__ __launch_bounds__(256) void out_gemm(
    const ushort* __restrict__ A, const ushort* __restrict__ BT,
    const float* __restrict__ bo, float* __restrict__ out)
{
    __shared__ char smem[32768];
    ushort* Ab = (ushort*)smem;
    ushort* Bb = (ushort*)(smem + 16384);

    const int n0 = blockIdx.x * 128, m0 = blockIdx.y * 128;
    const int tid = threadIdx.x, lane = tid & 63, wid = tid >> 6;
    const int wr = wid >> 1, wc = wid & 1;
    const int lr = lane >> 3, lk = (lane & 7) * 8;

    f32x4 acc[4][4];
#pragma unroll
    for (int i = 0; i < 4; ++i)
#pragma unroll
        for (int j = 0; j < 4; ++j) acc[i][j] = (f32x4){0.f, 0.f, 0.f, 0.f};

    for (int k0 = 0; k0 < EMB; k0 += 64) {
#pragma unroll
        for (int t = 0; t < 4; ++t) {
            int c = wid * 4 + t;
            int row = c * 8 + lr;
            gload16(A  + (size_t)(m0 + row) * EMB + k0 + lk, Ab + c * 512);
            gload16(BT + (size_t)(n0 + row) * EMB + k0 + lk, Bb + c * 512);
        }
        __syncthreads();
#pragma unroll
        for (int ks = 0; ks < 2; ++ks) {
            bf16x8 fa[4], fb[4];
#pragma unroll
            for (int f = 0; f < 4; ++f) {
                int koff = ks * 32 + (lane >> 4) * 8;
                fa[f] = *(const bf16x8*)(Ab + (wr * 64 + f * 16 + (lane & 15)) * 64 + koff);
                fb[f] = *(const bf16x8*)(Bb + (wc * 64 + f * 16 + (lane & 15)) * 64 + koff);
            }
#pragma unroll
            for (int i = 0; i < 4; ++i)
#pragma unroll
                for (int j = 0; j < 4; ++j)
                    acc[i][j] = MFMA(fa[i], fb[j], acc[i][j]);
        }
        __syncthreads();
    }

#pragma unroll
    for (int i = 0; i < 4; ++i) {
        int row = m0 + wr * 64 + i * 16 + (lane >> 4) * 4;
#pragma unroll
        for (int j = 0; j < 4; ++j) {
            int col = n0 + wc * 64 + j * 16 + (lane & 15);
            float bias = bo[col];
#pragma unroll
            for (int r = 0; r < 4; ++r)
                out[(size_t)(row + r) * EMB + col] = acc[i][j][r] + bias;
        }
    }
}

// ---------------------------------------------------------------------------
extern "C" void kernel_launch(void* const* d_in, const int* in_sizes, int n_in,
                              void* d_out, int out_size, void* d_ws, size_t ws_size,
                              hipStream_t stream)
{
    const float* x  = (const float*)d_in[0];
    const float* Wq = (const float*)d_in[1];
    const float* Wk = (const float*)d_in[2];
    const float* Wv = (const float*)d_in[3];
    const float* Wo = (const float*)d_in[4];
    const float* bo = (const float*)d_in[5];
    float* out = (float*)d_out;

    char* ws = (char*)d_ws;                      // 56 MB used (<= 67 MB known OK)
    ushort* xbf  = (ushort*)(ws);                // [4096][1024]  8 MB
    ushort* WT   = (ushort*)(ws + (8  << 20));   // [3072][1024]  6 MB
    ushort* Wobf = (ushort*)(ws + (14 << 20));   // [1024][1024]  2 MB
    ushort* qtok = (ushort*)(ws + (16 << 20));   // [4096][3072] 24 MB
    ushort* VT   = (ushort*)(ws + (40 << 20));   // [32][64][2048] 8 MB
    ushort* Ybf  = (ushort*)(ws + (48 << 20));   // [4096][1024]  8 MB

    f32_to_bf16<<<2048, 256, 0, stream>>>(x,  xbf,  NTOK * EMB / 8);
    f32_to_bf16<<<512,  256, 0, stream>>>(Wo, Wobf, EMB * EMB / 8);
    build_wallt<<<dim3(16, 48), 256, 0, stream>>>(Wq, Wk, Wv, WT);
    qkv_gemm<<<dim3(24, 32), 256, 0, stream>>>(xbf, WT, qtok);
    transpose_v<<<dim3(32, 32), 256, 0, stream>>>(qtok, VT);
    attn_mfma<<<dim3(16, 32), 256, 0, stream>>>(qtok, VT, Ybf);
    out_gemm<<<dim3(8, 32), 256, 0, stream>>>(Ybf, Wobf, bo, out);
}